// Round 9
// baseline (183.281 us; speedup 1.0000x reference)
//
#include <hip/hip_runtime.h>
#include <math.h>

#define BB 2
#define CC 512
#define NN 2304
#define NH 8
#define DD 512
#define D3 1536
#define WIDTH 48
#define C1 0.18033688f  // 0.125 * log2(e)

typedef _Float16 h8 __attribute__((ext_vector_type(8)));
typedef _Float16 h4 __attribute__((ext_vector_type(4)));
typedef _Float16 h2 __attribute__((ext_vector_type(2)));
typedef float f4 __attribute__((ext_vector_type(4)));

__device__ __forceinline__ void gload16(const void* g, void* s) {
  __builtin_amdgcn_global_load_lds(
      (const __attribute__((address_space(1))) unsigned int*)g,
      (__attribute__((address_space(3))) unsigned int*)s, 16, 0, 0);
}

// ---------------------------------------------------------------------------
// Kernel 0: fused prep (unchanged from R8). blockIdx.y selects job.
// ---------------------------------------------------------------------------
__global__ __launch_bounds__(256) void prep_k(
    const float* __restrict__ x, const float* __restrict__ wq,
    const float* __restrict__ wo, const float* __restrict__ wavp,
    _Float16* __restrict__ btf, _Float16* __restrict__ xt,
    _Float16* __restrict__ wqh, _Float16* __restrict__ woh)
{
  __shared__ float Ls[32][33];
  const int t = threadIdx.x;
  const int bx = blockIdx.x;
  const int job = blockIdx.y;

  if (job == 0) {
    if (bx >= 648) return;
    const int gid = bx * 256 + t;
    const int tile = gid >> 7, tid = gid & 127;
    const int qbk = tile / 36, ktk = tile % 36;
    const int w = tid >> 6, quad = (tid >> 4) & 3, l15 = tid & 15;
    const float pc = 6.283185307179586f / (fabsf(wavp[0]) * (float)WIDTH + 1e-6f);
    _Float16* o = btf + (((size_t)qbk * 36 + ktk) * 128 + tid) * 32;
#pragma unroll
    for (int g = 0; g < 4; ++g) {
      h8 v;
#pragma unroll
      for (int e = 0; e < 8; ++e) {
        const int j = g * 8 + e;
        const int nt = j >> 4, mt = (j >> 2) & 3, r = j & 3;
        const int q = qbk * 64 + w * 32 + nt * 16 + l15;
        const int k = ktk * 64 + mt * 16 + quad * 4 + r;
        const float dy = (float)(q / WIDTH) - (float)(k / WIDTH);
        const float dx = (float)(q % WIDTH) - (float)(k % WIDTH);
        const float dist = sqrtf(dy * dy + dx * dx + 1e-8f);
        v[e] = (_Float16)(0.1f * __cosf(dist * pc) * 1.44269504f);
      }
      *(h8*)(o + g * 8) = v;
    }
  } else if (job == 1) {
    const int b = bx / 1152, rem = bx % 1152;
    const int c0 = (rem / 72) * 32, n0 = (rem % 72) * 32;
#pragma unroll
    for (int p = 0; p < 4; ++p) {
      const int cl = (t >> 5) + p * 8, nl = t & 31;
      Ls[cl][nl] = x[((size_t)b * CC + c0 + cl) * NN + n0 + nl];
    }
    __syncthreads();
#pragma unroll
    for (int p = 0; p < 2; ++p) {
      const int nl = (t >> 4) + p * 16, cl = (t & 15) * 2;
      h2 v = {(_Float16)Ls[cl][nl], (_Float16)Ls[cl + 1][nl]};
      *(h2*)(xt + ((size_t)b * NN + n0 + nl) * CC + c0 + cl) = v;
    }
  } else {
    if (bx >= 1024) return;
    const int idx = bx * 256 + t;
    const int NQ = (D3 * CC) / 4;
    if (idx < NQ) {
      float4 v = *(const float4*)(wq + (size_t)idx * 4);
      h4 o = {(_Float16)v.x, (_Float16)v.y, (_Float16)v.z, (_Float16)v.w};
      *(h4*)(wqh + (size_t)idx * 4) = o;
    } else {
      const int j = idx - NQ;
      float4 v = *(const float4*)(wo + (size_t)j * 4);
      h4 o = {(_Float16)v.x, (_Float16)v.y, (_Float16)v.z, (_Float16)v.w};
      *(h4*)(woh + (size_t)j * 4) = o;
    }
  }
}

// ---------------------------------------------------------------------------
// Kernel 1: qkv MFMA GEMM (unchanged from R8). 128x64 tile, 2 waves,
// double-buffered gload16 staging.
// ---------------------------------------------------------------------------
__global__ __launch_bounds__(128) void qkv_gemm_k(
    const _Float16* __restrict__ xt, const _Float16* __restrict__ wqh,
    _Float16* __restrict__ qb, _Float16* __restrict__ kb,
    _Float16* __restrict__ vb)
{
  __shared__ _Float16 Xs[2][128][32];
  __shared__ _Float16 Ws[2][64][32];
  const int t = threadIdx.x;
  const int lane = t & 63, w = t >> 6;
  const int l15 = lane & 15, quad = lane >> 4;
  const int n0 = blockIdx.x * 128;
  const int d0 = blockIdx.y * 64;
  const int b  = blockIdx.z;
  const bool isv = (d0 >= 2 * DD);
  const _Float16* xb = xt + (size_t)b * NN * CC;
  const int lrow = lane >> 2, lcol = (lane & 3) * 8;

  f4 acc[4][4];
#pragma unroll
  for (int mt = 0; mt < 4; ++mt)
#pragma unroll
    for (int nt = 0; nt < 4; ++nt) acc[mt][nt] = (f4)(0.f);

  auto stage = [&](int bf, int c0) {
#pragma unroll
    for (int k = 0; k < 4; ++k) {
      const int row = w * 64 + k * 16 + lrow;
      gload16(xb + (size_t)(n0 + row) * CC + c0 + lcol,
              &Xs[bf][w * 64 + k * 16][0]);
    }
#pragma unroll
    for (int k = 0; k < 2; ++k) {
      const int row = w * 32 + k * 16 + lrow;
      gload16(wqh + (size_t)(d0 + row) * CC + c0 + lcol,
              &Ws[bf][w * 32 + k * 16][0]);
    }
  };

  stage(0, 0);
  for (int i = 0; i < 16; ++i) {
    const int cur = i & 1;
    __syncthreads();
    if (i < 15) stage(cur ^ 1, (i + 1) * 32);
    h8 wfr[4], xfr[4];
#pragma unroll
    for (int mt = 0; mt < 4; ++mt)
      wfr[mt] = *(const h8*)&Ws[cur][mt * 16 + l15][quad * 8];
#pragma unroll
    for (int nt = 0; nt < 4; ++nt)
      xfr[nt] = *(const h8*)&Xs[cur][w * 64 + nt * 16 + l15][quad * 8];
    if (!isv) {
#pragma unroll
      for (int mt = 0; mt < 4; ++mt)
#pragma unroll
        for (int nt = 0; nt < 4; ++nt)
          acc[mt][nt] = __builtin_amdgcn_mfma_f32_16x16x32_f16(
              wfr[mt], xfr[nt], acc[mt][nt], 0, 0, 0);
    } else {
#pragma unroll
      for (int mt = 0; mt < 4; ++mt)
#pragma unroll
        for (int nt = 0; nt < 4; ++nt)
          acc[mt][nt] = __builtin_amdgcn_mfma_f32_16x16x32_f16(
              xfr[nt], wfr[mt], acc[mt][nt], 0, 0, 0);
    }
  }

  if (!isv) {
    const int which = d0 >> 9;
    _Float16* buf = which == 0 ? qb : kb;
    const int h = (d0 & 511) >> 6;
#pragma unroll
    for (int mt = 0; mt < 4; ++mt) {
      const int dh = mt * 16 + quad * 4;
#pragma unroll
      for (int nt = 0; nt < 4; ++nt) {
        const int token = n0 + w * 64 + nt * 16 + l15;
        h4 o = {(_Float16)acc[mt][nt][0], (_Float16)acc[mt][nt][1],
                (_Float16)acc[mt][nt][2], (_Float16)acc[mt][nt][3]};
        *(h4*)(buf + (((size_t)b * NH + h) * NN + token) * 64 + dh) = o;
      }
    }
  } else {
    const int h = (d0 - 2 * DD) >> 6;
#pragma unroll
    for (int mt = 0; mt < 4; ++mt) {
      const int dh = mt * 16 + l15;
#pragma unroll
      for (int nt = 0; nt < 4; ++nt) {
        const int token = n0 + w * 64 + nt * 16 + quad * 4;
        h4 o = {(_Float16)acc[mt][nt][0], (_Float16)acc[mt][nt][1],
                (_Float16)acc[mt][nt][2], (_Float16)acc[mt][nt][3]};
        *(h4*)(vb + (((size_t)b * NH + h) * 64 + dh) * NN + token) = o;
      }
    }
  }
}

// ---------------------------------------------------------------------------
// Kernel 2: MFMA flash attention. 4 waves/block, q-tile 128 (32 q/wave),
// shared K/V LDS staging (amortized over 4 waves), runtime K-split (2 or 4).
// No-max softmax; bias from frag-ordered table; R4-proven loop structure.
// ---------------------------------------------------------------------------
__global__ __launch_bounds__(256, 4) void attn_k(
    const _Float16* __restrict__ qb, const _Float16* __restrict__ kb,
    const _Float16* __restrict__ vb, const _Float16* __restrict__ btf,
    _Float16* __restrict__ op, float* __restrict__ lp,
    int slog, int ktiles)
{
  __shared__ _Float16 Ks[64][72];
  __shared__ _Float16 Vs[64][72];
  __shared__ _Float16 Ps[4][32][72];

  const int t    = threadIdx.x;
  const int lane = t & 63;
  const int w    = t >> 6;        // wave 0..3
  const int l15  = lane & 15;
  const int quad = lane >> 4;
  const int qsub = w >> 1;        // 64-q subtile within the 128-q block
  const int wp   = w & 1;         // wave parity within subtile
  const int qt   = blockIdx.x >> slog;        // 128-q tile 0..17
  const int s    = blockIdx.x & ((1 << slog) - 1);  // k-split index
  const int h = blockIdx.y, b = blockIdx.z;
  const int qt64 = qt * 2 + qsub;
  const int qbase = qt64 * 64 + wp * 32;      // this wave's 32-query base
  const size_t base = ((size_t)b * NH + h) * NN * 64;
  const _Float16* qp = qb + base;
  const _Float16* kp = kb + base;
  const _Float16* vp = vb + base;  // [dh][n]

  h8 qf[2][2];
#pragma unroll
  for (int nt = 0; nt < 2; ++nt)
#pragma unroll
    for (int ks = 0; ks < 2; ++ks)
      qf[nt][ks] = *(const h8*)(qp + (size_t)(qbase + nt * 16 + l15) * 64 +
                                ks * 32 + quad * 8);

  f4 oc[4][2];
#pragma unroll
  for (int mt = 0; mt < 4; ++mt)
#pragma unroll
    for (int nt = 0; nt < 2; ++nt) oc[mt][nt] = (f4)(0.f);
  float lacc[2][4] = {};

  // staging: 256 threads, each 2 rows (sr, sr+32), one h8 chunk per row
  const int sr = t >> 3, so = (t & 7) * 8;
  const int tid128 = wp * 64 + lane;
  const _Float16* bp =
      btf + (((size_t)qt64 * 36 + s * ktiles) * 128 + tid128) * 32;

  for (int kt = 0; kt < ktiles; ++kt) {
    const int k0 = (s * ktiles + kt) * 64;
    h8 kr[2], vr[2], br[4];
#pragma unroll
    for (int r = 0; r < 2; ++r) {
      const int row = sr + r * 32;
      kr[r] = *(const h8*)(kp + (size_t)(k0 + row) * 64 + so);
      vr[r] = *(const h8*)(vp + (size_t)row * NN + k0 + so);
    }
#pragma unroll
    for (int r = 0; r < 4; ++r) br[r] = *(const h8*)(bp + r * 8);
    bp += 128 * 32;
    __syncthreads();  // all waves done reading previous tile's LDS
#pragma unroll
    for (int r = 0; r < 2; ++r) {
      const int row = sr + r * 32;
      *(h8*)&Ks[row][so] = kr[r];
      *(h8*)&Vs[row][so] = vr[r];
    }
    __syncthreads();

    // ---- S^T = K * Q^T ----
    f4 st[4][2];
#pragma unroll
    for (int mt = 0; mt < 4; ++mt)
#pragma unroll
      for (int nt = 0; nt < 2; ++nt) st[mt][nt] = (f4)(0.f);
#pragma unroll
    for (int ks = 0; ks < 2; ++ks)
#pragma unroll
      for (int mt = 0; mt < 4; ++mt) {
        h8 kf = *(const h8*)&Ks[mt * 16 + l15][ks * 32 + quad * 8];
#pragma unroll
        for (int nt = 0; nt < 2; ++nt)
          st[mt][nt] = __builtin_amdgcn_mfma_f32_16x16x32_f16(
              kf, qf[nt][ks], st[mt][nt], 0, 0, 0);
      }

    // ---- p = exp2(s*C1 + bias'), no max tracking ----
#pragma unroll
    for (int nt = 0; nt < 2; ++nt) {
      const int q = nt * 16 + l15;
#pragma unroll
      for (int mt = 0; mt < 4; ++mt) {
        h4 pk;
#pragma unroll
        for (int r = 0; r < 4; ++r) {
          const int j = nt * 16 + mt * 4 + r;
          const float bias = (float)br[j >> 3][j & 7];
          const float p = __builtin_exp2f(st[mt][nt][r] * C1 + bias);
          lacc[nt][r] += p;
          pk[r] = (_Float16)p;
        }
        *(h4*)&Ps[w][q][mt * 16 + quad * 4] = pk;  // wave-private
      }
    }

    // ---- O^T += V^T * P^T ----
#pragma unroll
    for (int ks = 0; ks < 2; ++ks) {
      h8 pf[2];
#pragma unroll
      for (int nt = 0; nt < 2; ++nt)
        pf[nt] = *(const h8*)&Ps[w][nt * 16 + l15][ks * 32 + quad * 8];
#pragma unroll
      for (int mt = 0; mt < 4; ++mt) {
        h8 vf = *(const h8*)&Vs[mt * 16 + l15][ks * 32 + quad * 8];
#pragma unroll
        for (int nt = 0; nt < 2; ++nt)
          oc[mt][nt] = __builtin_amdgcn_mfma_f32_16x16x32_f16(
              vf, pf[nt], oc[mt][nt], 0, 0, 0);
      }
    }
  }

  // ---- epilogue: normalized partial O (f16) + l (f32), per split ----
#pragma unroll
  for (int nt = 0; nt < 2; ++nt) {
    float l = lacc[nt][0] + lacc[nt][1] + lacc[nt][2] + lacc[nt][3];
    l += __shfl_xor(l, 16);
    l += __shfl_xor(l, 32);
    const float inv = 1.f / l;
    const int qi = qbase + nt * 16 + l15;
    _Float16* od = op + (size_t)s * BB * NN * DD +
                   ((size_t)b * NN + qi) * DD + h * 64;
#pragma unroll
    for (int mt = 0; mt < 4; ++mt) {
      const int dh = mt * 16 + quad * 4;
      h4 o = {(_Float16)(oc[mt][nt][0] * inv), (_Float16)(oc[mt][nt][1] * inv),
              (_Float16)(oc[mt][nt][2] * inv), (_Float16)(oc[mt][nt][3] * inv)};
      *(h4*)(od + dh) = o;
    }
    if (quad == 0)
      lp[(size_t)s * BB * NH * NN + ((size_t)b * NH + h) * NN + qi] = l;
  }
}

// ---------------------------------------------------------------------------
// Kernel 3: fused split-combine + out-projection GEMM, software-pipelined:
// next iteration's op/lp raw loads AND W staging issued right after the
// barrier so their latency hides under combine+MFMA. One barrier per iter.
// ---------------------------------------------------------------------------
template <int NS>
__global__ __launch_bounds__(64) void outcomb_k(
    const _Float16* __restrict__ op, const float* __restrict__ lp,
    const _Float16* __restrict__ woh, const float* __restrict__ bias,
    float* __restrict__ out)
{
  __shared__ _Float16 Hs[64][32];
  __shared__ _Float16 Ws2[2][64][32];
  const int t = threadIdx.x;
  const int l15 = t & 15, quad = t >> 4;
  const int n0 = blockIdx.x * 64;
  const int o0 = blockIdx.y * 64;
  const int b  = blockIdx.z;
  const int lrow = t >> 2, lcol = (t & 3) * 8;
  const size_t SZO = (size_t)BB * NN * DD;
  const size_t SZL = (size_t)BB * NH * NN;

  f4 acc[4][4];
#pragma unroll
  for (int mt = 0; mt < 4; ++mt)
#pragma unroll
    for (int nt = 0; nt < 4; ++nt) acc[mt][nt] = (f4)(0.f);

  auto stage_w = [&](int bf, int c0) {
#pragma unroll
    for (int k = 0; k < 4; ++k)
      gload16(woh + (size_t)(o0 + k * 16 + lrow) * DD + c0 + lcol,
              &Ws2[bf][k * 16][0]);
  };

  float lv[4][NS];
  h8 ov[4][NS];
  auto load_raw = [&](int i) {
    const int c0 = i * 32, h = c0 >> 6;
#pragma unroll
    for (int k = 0; k < 4; ++k) {
      const int row = n0 + k * 16 + lrow;
      const size_t off = ((size_t)b * NN + row) * DD + c0 + lcol;
#pragma unroll
      for (int s = 0; s < NS; ++s) {
        lv[k][s] = lp[s * SZL + ((size_t)b * NH + h) * NN + row];
        ov[k][s] = *(const h8*)(op + s * SZO + off);
      }
    }
  };

  stage_w(0, 0);
  load_raw(0);
  for (int i = 0; i < 16; ++i) {
    const int cur = i & 1;
    __syncthreads();  // Ws2[cur] staged; prior Hs reads done
    if (i < 15) stage_w(cur ^ 1, (i + 1) * 32);  // in flight this iter
    // combine current raw regs -> Hs
#pragma unroll
    for (int k = 0; k < 4; ++k) {
      float tot = 0.f;
#pragma unroll
      for (int s = 0; s < NS; ++s) tot += lv[k][s];
      const float inv = 1.f / tot;
      float wgt[NS];
#pragma unroll
      for (int s = 0; s < NS; ++s) wgt[s] = lv[k][s] * inv;
      h8 a;
#pragma unroll
      for (int e = 0; e < 8; ++e) {
        float v = 0.f;
#pragma unroll
        for (int s = 0; s < NS; ++s) v += (float)ov[k][s][e] * wgt[s];
        a[e] = (_Float16)v;
      }
      *(h8*)&Hs[k * 16 + lrow][lcol] = a;
    }
    if (i < 15) load_raw(i + 1);  // latency hides under MFMAs below
    h8 hf[4], wf[4];
#pragma unroll
    for (int mt = 0; mt < 4; ++mt)
      hf[mt] = *(const h8*)&Hs[mt * 16 + l15][quad * 8];
#pragma unroll
    for (int nt = 0; nt < 4; ++nt)
      wf[nt] = *(const h8*)&Ws2[cur][nt * 16 + l15][quad * 8];
#pragma unroll
    for (int mt = 0; mt < 4; ++mt)
#pragma unroll
      for (int nt = 0; nt < 4; ++nt)
        acc[mt][nt] = __builtin_amdgcn_mfma_f32_16x16x32_f16(
            hf[mt], wf[nt], acc[mt][nt], 0, 0, 0);
  }

#pragma unroll
  for (int nt = 0; nt < 4; ++nt) {
    const int o = o0 + nt * 16 + l15;
    const float bv = bias[o];
#pragma unroll
    for (int mt = 0; mt < 4; ++mt) {
      const int token = n0 + mt * 16 + quad * 4;
      float4 v = {acc[mt][nt][0] + bv, acc[mt][nt][1] + bv,
                  acc[mt][nt][2] + bv, acc[mt][nt][3] + bv};
      *(float4*)(out + ((size_t)b * DD + o) * NN + token) = v;
    }
  }
}

extern "C" void kernel_launch(void* const* d_in, const int* in_sizes, int n_in,
                              void* d_out, int out_size, void* d_ws, size_t ws_size,
                              hipStream_t stream)
{
  (void)in_sizes; (void)n_in; (void)out_size;
  const float* x     = (const float*)d_in[0];
  const float* w_qkv = (const float*)d_in[1];
  const float* w_out = (const float*)d_in[2];
  const float* b_out = (const float*)d_in[3];
  const float* wav   = (const float*)d_in[4];
  float* out = (float*)d_out;

  const size_t SZ  = (size_t)BB * NH * NN * 64;   // 2,359,296 (h16)
  const size_t BTF = (size_t)36 * 36 * 128 * 32;  // 5,308,416 (h16)

  // ws needed at NSPLIT=4: 3*SZ*2 + BTF*2 + 4*SZ*2 + 4*B*NH*NN*4 + DD*DD*2
  //                      = 44,761,088 B. Fall back to NSPLIT=2 (35.0 MB) if
  // ws is smaller (R1 proved >= ~37.7 MB available).
  const size_t need4 = 3 * SZ * 2 + BTF * 2 + 4 * SZ * 2 +
                       4 * (size_t)BB * NH * NN * 4 + (size_t)DD * DD * 2;
  const int nsplit = (ws_size >= need4) ? 4 : 2;
  const int slog   = (nsplit == 4) ? 2 : 1;
  const int ktiles = 36 / nsplit;

  _Float16* qb  = (_Float16*)d_ws;
  _Float16* kb  = qb + SZ;
  _Float16* vb  = kb + SZ;
  _Float16* btf = vb + SZ;
  _Float16* op  = btf + BTF;                       // nsplit*SZ partial O (f16)
  float*    lpf = (float*)(op + (size_t)nsplit * SZ);
  _Float16* woh = (_Float16*)(lpf + (size_t)nsplit * BB * NH * NN);
  // aliases (lifetime-disjoint):
  _Float16* xt  = op;        // x^T f16, dead after qkv_gemm
  _Float16* wqh = op + SZ;   // w_qkv f16, dead after qkv_gemm

  prep_k    <<<dim3(2304, 3), 256, 0, stream>>>(x, w_qkv, w_out, wav,
                                                btf, xt, wqh, woh);
  qkv_gemm_k<<<dim3(NN / 128, D3 / 64, BB), 128, 0, stream>>>(xt, wqh, qb, kb, vb);
  attn_k    <<<dim3((NN / 128) * nsplit, NH, BB), 256, 0, stream>>>(
                 qb, kb, vb, btf, op, lpf, slog, ktiles);
  if (nsplit == 4)
    outcomb_k<4><<<dim3(NN / 64, DD / 64, BB), 64, 0, stream>>>(
                   op, lpf, woh, b_out, out);
  else
    outcomb_k<2><<<dim3(NN / 64, DD / 64, BB), 64, 0, stream>>>(
                   op, lpf, woh, b_out, out);
}